// Round 5
// baseline (90.540 us; speedup 1.0000x reference)
//
#include <hip/hip_runtime.h>

// ChebFCN2D: out[n,o] = b[o] + W[o,0] + sum_{i=1..31} T_i(x) * (sum_{j=1..31} W[o,1+(i-1)*31+(j-1)] * T_j(y))
// N = 262144 points, W: [3,962] f32, out: [N,3] f32.
// VALU-bound. W reads are wave-uniform -> s_load via K$. 2 points/thread so each
// loaded W dword feeds 2x FMAs -> s_load latency hidden behind ~372 issue-cycles/chunk.

#define LSZ 32      // T_0..T_31
#define FEAT 962
#define PTS 2

__global__ __launch_bounds__(256) void cheb_fcn2d_kernel(
    const float* __restrict__ x,   // [N,2]
    const float* __restrict__ W,   // [3,962]
    const float* __restrict__ b,   // [3]
    float* __restrict__ out,       // [N,3]
    int N)
{
    int t = blockIdx.x * blockDim.x + threadIdx.x;
    int n0 = t * PTS;
    if (n0 >= N) return;

    // Two consecutive points: (x0,y0,x1,y1) in one 16B load.
    float4 xy = *reinterpret_cast<const float4*>(x + 2 * (size_t)n0);
    float x0 = xy.x, y0 = xy.y;
    float x1 = xy.z, y1 = xy.w;

    // Chebyshev features of y for both points, fully unrolled (compile-time reg indices).
    float Ya[LSZ], Yb[LSZ];
    Ya[0] = 1.0f; Ya[1] = y0;
    Yb[0] = 1.0f; Yb[1] = y1;
    float ty2a = 2.0f * y0, ty2b = 2.0f * y1;
#pragma unroll
    for (int k = 2; k < LSZ; ++k) {
        Ya[k] = ty2a * Ya[k - 1] - Ya[k - 2];
        Yb[k] = ty2b * Yb[k - 1] - Yb[k - 2];
    }

    float w00 = W[0 * FEAT], w10 = W[1 * FEAT], w20 = W[2 * FEAT];
    float b0 = b[0], b1 = b[1], b2 = b[2];
    float a00 = b0 + w00, a01 = b1 + w10, a02 = b2 + w20;  // point 0: out 0,1,2
    float a10 = b0 + w00, a11 = b1 + w10, a12 = b2 + w20;  // point 1

    // Rolling Chebyshev recurrence for x (no runtime-indexed reg arrays).
    float tx2a = 2.0f * x0, tx2b = 2.0f * x1;
    float xpp_a = 1.0f, xp_a = x0;
    float xpp_b = 1.0f, xp_b = x1;

    for (int i = 1; i < LSZ; ++i) {
        const int base = 1 + (i - 1) * (LSZ - 1) - 1;  // W[o*FEAT + base + j]

        // 6 independent FMA chains (3 outputs x 2 points) -> latency covered.
        float s0a = 0.f, s1a = 0.f, s2a = 0.f;
        float s0b = 0.f, s1b = 0.f, s2b = 0.f;
#pragma unroll
        for (int j = 1; j < LSZ; ++j) {
            float wv0 = W[0 * FEAT + base + j];
            float wv1 = W[1 * FEAT + base + j];
            float wv2 = W[2 * FEAT + base + j];
            s0a += wv0 * Ya[j];
            s0b += wv0 * Yb[j];
            s1a += wv1 * Ya[j];
            s1b += wv1 * Yb[j];
            s2a += wv2 * Ya[j];
            s2b += wv2 * Yb[j];
        }

        a00 += xp_a * s0a;
        a01 += xp_a * s1a;
        a02 += xp_a * s2a;
        a10 += xp_b * s0b;
        a11 += xp_b * s1b;
        a12 += xp_b * s2b;

        float xn_a = tx2a * xp_a - xpp_a;
        xpp_a = xp_a; xp_a = xn_a;
        float xn_b = tx2b * xp_b - xpp_b;
        xpp_b = xp_b; xp_b = xn_b;
    }

    // 6 consecutive floats at out + 3*n0 (8B-aligned since 3*n0 is even).
    float2* o2 = reinterpret_cast<float2*>(out + 3 * (size_t)n0);
    o2[0] = make_float2(a00, a01);
    o2[1] = make_float2(a02, a10);
    o2[2] = make_float2(a11, a12);
}

extern "C" void kernel_launch(void* const* d_in, const int* in_sizes, int n_in,
                              void* d_out, int out_size, void* d_ws, size_t ws_size,
                              hipStream_t stream) {
    const float* x = (const float*)d_in[0];   // [N,2]
    const float* W = (const float*)d_in[1];   // [3,962]
    const float* b = (const float*)d_in[2];   // [3]
    float* out = (float*)d_out;               // [N,3]

    int N = in_sizes[0] / 2;
    int block = 256;
    int threads_needed = (N + PTS - 1) / PTS;
    int grid = (threads_needed + block - 1) / block;
    cheb_fcn2d_kernel<<<grid, block, 0, stream>>>(x, W, b, out, N);
}

// Round 8
// 80.262 us; speedup vs baseline: 1.1281x; 1.1281x over previous
//
#include <hip/hip_runtime.h>

// ChebFCN2D: out[n,o] = b[o] + W[o,0] + sum_{i=1..31} T_i(x) * (sum_{j=1..31} W[o,1+(i-1)*31+(j-1)] * T_j(y))
// N = 262144 points, W: [3,962] f32, out: [N,3] f32.
// Kernel is VALU-issue-bound (~10.3 us fp32 floor); dur_us metric carries ~80 us of
// harness poison-fills. This round: v_dot2_f32_f16 (2 MAC/instr, f32 accum) via
// pre-packed f16 W pairs in d_ws. half2_t is __fp16-based to match builtin types.

#define LSZ 32      // T_0..T_31
#define FEAT 962
#define PTS 2
#define NPAIR 16    // 31 j-terms -> 16 half2 pairs (last padded with 0)
#define NROWS 31    // i = 1..31
#define WH_COUNT (NROWS * 3 * NPAIR)   // 1488 half2

typedef __fp16 half2_t __attribute__((ext_vector_type(2)));

#if defined(__HIP_DEVICE_COMPILE__) && defined(__has_builtin)
#if __has_builtin(__builtin_amdgcn_fdot2) && __has_builtin(__builtin_amdgcn_cvt_pkrtz)
#define USE_DOT2 1
#endif
#endif
#ifndef USE_DOT2
#define USE_DOT2 0
#endif

// Pack W[o, 1 + (i-1)*31 + jj] (jj=0..30, 0-pad to 32) into half2 pairs,
// layout Wh[((i-1)*3 + o)*16 + p] = (w_{jj=2p}, w_{jj=2p+1}).
__global__ void cheb_pack_w_kernel(const float* __restrict__ W, half2_t* __restrict__ Wh) {
    int q = blockIdx.x * blockDim.x + threadIdx.x;
    if (q >= WH_COUNT) return;
    int i_idx = q / (3 * NPAIR);
    int r = q % (3 * NPAIR);
    int o = r / NPAIR;
    int p = r % NPAIR;
    int jj = 2 * p;
    const float* row = W + o * FEAT + 1 + i_idx * 31;
    float a = row[jj];
    float bv = (jj + 1 < 31) ? row[jj + 1] : 0.f;
#if USE_DOT2
    Wh[q] = __builtin_amdgcn_cvt_pkrtz(a, bv);
#else
    half2_t h;
    h.x = (__fp16)a;
    h.y = (__fp16)bv;
    Wh[q] = h;
#endif
}

__global__ __launch_bounds__(256) void cheb_fcn2d_kernel(
    const float* __restrict__ x,    // [N,2]
    const float* __restrict__ W,    // [3,962] (fp32; used for W[o,0] and fallback)
    const half2_t* __restrict__ Wh, // [1488] packed f16 pairs
    const float* __restrict__ b,    // [3]
    float* __restrict__ out,        // [N,3]
    int N)
{
    int t = blockIdx.x * blockDim.x + threadIdx.x;
    int n0 = t * PTS;
    if (n0 >= N) return;

    float4 xy = *reinterpret_cast<const float4*>(x + 2 * (size_t)n0);
    float x0 = xy.x, y0 = xy.y;
    float x1 = xy.z, y1 = xy.w;

    float w00 = W[0 * FEAT], w10 = W[1 * FEAT], w20 = W[2 * FEAT];
    float accA[3], accB[3];
    accA[0] = b[0] + w00; accA[1] = b[1] + w10; accA[2] = b[2] + w20;
    accB[0] = accA[0];    accB[1] = accA[1];    accB[2] = accA[2];

    // Rolling Chebyshev recurrence for x.
    float tx2a = 2.0f * x0, tx2b = 2.0f * x1;
    float xpp_a = 1.0f, xp_a = x0;
    float xpp_b = 1.0f, xp_b = x1;

#if USE_DOT2
    // Build Y pairs in f16: Yh[p] = (T_{2p+1}(y), T_{2p+2}(y)), p=0..14; Yh[15]=(T_31, 0).
    half2_t Yha[NPAIR], Yhb[NPAIR];
    {
        float ty2 = 2.0f * y0;
        float tpp = 1.0f, tp = y0;   // T0, T1
#pragma unroll
        for (int p = 0; p < 15; ++p) {
            float first = tp;                 // T_{2p+1}
            float tc = ty2 * tp - tpp;        // T_{2p+2}
            float tn = ty2 * tc - tp;         // T_{2p+3}
            Yha[p] = __builtin_amdgcn_cvt_pkrtz(first, tc);
            tpp = tc; tp = tn;
        }
        Yha[15] = __builtin_amdgcn_cvt_pkrtz(tp, 0.f);  // (T_31, 0)
    }
    {
        float ty2 = 2.0f * y1;
        float tpp = 1.0f, tp = y1;
#pragma unroll
        for (int p = 0; p < 15; ++p) {
            float first = tp;
            float tc = ty2 * tp - tpp;
            float tn = ty2 * tc - tp;
            Yhb[p] = __builtin_amdgcn_cvt_pkrtz(first, tc);
            tpp = tc; tp = tn;
        }
        Yhb[15] = __builtin_amdgcn_cvt_pkrtz(tp, 0.f);
    }

    for (int i = 1; i < LSZ; ++i) {
        const half2_t* wrow = Wh + (size_t)(i - 1) * (3 * NPAIR);  // wave-uniform -> s_load
#pragma unroll
        for (int o = 0; o < 3; ++o) {
            float sa = 0.f, sb = 0.f;
#pragma unroll
            for (int p = 0; p < NPAIR; ++p) {
                half2_t w = wrow[o * NPAIR + p];
                sa = __builtin_amdgcn_fdot2(w, Yha[p], sa, false);
                sb = __builtin_amdgcn_fdot2(w, Yhb[p], sb, false);
            }
            accA[o] += xp_a * sa;
            accB[o] += xp_b * sb;
        }
        float xn_a = tx2a * xp_a - xpp_a;
        xpp_a = xp_a; xp_a = xn_a;
        float xn_b = tx2b * xp_b - xpp_b;
        xpp_b = xp_b; xp_b = xn_b;
    }
#else
    // fp32 fallback (R5-proven path).
    float Ya[LSZ], Yb[LSZ];
    Ya[0] = 1.0f; Ya[1] = y0;
    Yb[0] = 1.0f; Yb[1] = y1;
    float ty2a = 2.0f * y0, ty2b = 2.0f * y1;
#pragma unroll
    for (int k = 2; k < LSZ; ++k) {
        Ya[k] = ty2a * Ya[k - 1] - Ya[k - 2];
        Yb[k] = ty2b * Yb[k - 1] - Yb[k - 2];
    }
    for (int i = 1; i < LSZ; ++i) {
        const int base = (i - 1) * (LSZ - 1);
        float s0a = 0.f, s1a = 0.f, s2a = 0.f;
        float s0b = 0.f, s1b = 0.f, s2b = 0.f;
#pragma unroll
        for (int j = 1; j < LSZ; ++j) {
            float wv0 = W[0 * FEAT + 1 + base + j - 1];
            float wv1 = W[1 * FEAT + 1 + base + j - 1];
            float wv2 = W[2 * FEAT + 1 + base + j - 1];
            s0a += wv0 * Ya[j];
            s0b += wv0 * Yb[j];
            s1a += wv1 * Ya[j];
            s1b += wv1 * Yb[j];
            s2a += wv2 * Ya[j];
            s2b += wv2 * Yb[j];
        }
        accA[0] += xp_a * s0a;
        accA[1] += xp_a * s1a;
        accA[2] += xp_a * s2a;
        accB[0] += xp_b * s0b;
        accB[1] += xp_b * s1b;
        accB[2] += xp_b * s2b;
        float xn_a = tx2a * xp_a - xpp_a;
        xpp_a = xp_a; xp_a = xn_a;
        float xn_b = tx2b * xp_b - xpp_b;
        xpp_b = xp_b; xp_b = xn_b;
    }
#endif

    float2* o2 = reinterpret_cast<float2*>(out + 3 * (size_t)n0);
    o2[0] = make_float2(accA[0], accA[1]);
    o2[1] = make_float2(accA[2], accB[0]);
    o2[2] = make_float2(accB[1], accB[2]);
}

extern "C" void kernel_launch(void* const* d_in, const int* in_sizes, int n_in,
                              void* d_out, int out_size, void* d_ws, size_t ws_size,
                              hipStream_t stream) {
    const float* x = (const float*)d_in[0];   // [N,2]
    const float* W = (const float*)d_in[1];   // [3,962]
    const float* b = (const float*)d_in[2];   // [3]
    float* out = (float*)d_out;               // [N,3]
    half2_t* Wh = (half2_t*)d_ws;             // 1488 * 4 B = 5952 B of d_ws

    int N = in_sizes[0] / 2;

    // Pack W -> f16 pairs (always launched; body is trivial either path).
    cheb_pack_w_kernel<<<(WH_COUNT + 255) / 256, 256, 0, stream>>>(W, Wh);

    int block = 256;
    int threads_needed = (N + PTS - 1) / PTS;
    int grid = (threads_needed + block - 1) / block;
    cheb_fcn2d_kernel<<<grid, block, 0, stream>>>(x, W, Wh, b, out, N);
}

// Round 11
// 65.739 us; speedup vs baseline: 1.3773x; 1.2209x over previous
//
#include <hip/hip_runtime.h>

// ChebFCN2D via MFMA. out[n,o] = b[o] + W[o,0] + sum_{i,j=1..31} W[o,1+(i-1)*31+(j-1)] Ti(x) Tj(y)
// Stage 1 (GEMM, mfma_f32_16x16x32_f16): Z[(o,i'),pt] = sum_k Wpad[(o,i'),k] * T_{k+1}(y_pt)
//   rows R = o*32 + i' (o=0..2, i'=0..31, rows with i'=31 zero-padded), K = 32 (k=31 zero-padded)
//   6 row-tiles of 16 -> 6 MFMAs per 16-point group.
// Stage 2 (VALU): out[o,pt] = sum_{i'} T_{i'+1}(x_pt) * Z[o*32+i', pt]
//   D-frag: col=lane&15 (point), row=4q+r (q=lane>>4)  [m89-verified]
//   global row = 16t+4q+r -> o = t>>1 (compile-time), i' = 16(t&1)+4q+r -> two ds_read_b128 of Tx.
// A-frag assumption: lane holds A[row=lane&15][k=8*(lane>>4)+e], e=0..7 (8 f16 = 4 VGPR).
// B-frag assumption: lane holds B[k=8*(lane>>4)+e][col=lane&15].
// LDS: Ty f16 [64][40], Tx f32 [64][40] (stride 40 breaks power-of-2 bank conflicts).

#define FEAT 962
#define TY_STRIDE 40
#define TX_STRIDE 40

typedef __fp16 half8_t __attribute__((ext_vector_type(8)));
typedef float f32x4 __attribute__((ext_vector_type(4)));

// Wpk[t][l][e] = Wpad[16t + (l&15)][8*(l>>4)+e], f16. 6*64*8 = 3072 f16 = 6 KB in d_ws.
__global__ void pack_w_kernel(const float* __restrict__ W, __fp16* __restrict__ Wpk) {
    int idx = blockIdx.x * blockDim.x + threadIdx.x;
    if (idx >= 6 * 64 * 8) return;
    int e = idx & 7;
    int l = (idx >> 3) & 63;
    int t = idx >> 9;
    int R = 16 * t + (l & 15);
    int k = 8 * (l >> 4) + e;
    int o = R >> 5;        // 0..2
    int ip = R & 31;       // i' = 0..31
    float v = (ip < 31 && k < 31) ? W[o * FEAT + 1 + ip * 31 + k] : 0.0f;
    Wpk[idx] = (__fp16)v;
}

__global__ __launch_bounds__(64) void cheb_mfma_kernel(
    const float* __restrict__ x,     // [N,2]
    const float* __restrict__ W,     // [3,962] (for W[o,0])
    const __fp16* __restrict__ Wpk,  // packed A-fragments
    const float* __restrict__ b,     // [3]
    float* __restrict__ out)         // [N,3]
{
    __shared__ __fp16 TyL[64 * TY_STRIDE];
    __shared__ float  TxL[64 * TX_STRIDE];

    const int l = threadIdx.x;        // 0..63
    const int q = l >> 4;             // 0..3
    const int p16 = l & 15;           // 0..15
    const long nb = (long)blockIdx.x * 64;

    // ---- per-point feature generation (lane l owns point nb+l) ----
    float2 xy = *reinterpret_cast<const float2*>(x + 2 * (nb + l));

    float tx[32], ty[32];
    {
        float c2 = 2.0f * xy.x;
        float tpp = 1.0f, tp = xy.x;
        tx[0] = tp;                         // T_1
#pragma unroll
        for (int m = 1; m < 31; ++m) {      // tx[m] = T_{m+1}
            float tc = c2 * tp - tpp;
            tx[m] = tc;
            tpp = tp; tp = tc;
        }
        tx[31] = 0.0f;                      // pad slot (multiplied by Z=0)
    }
    {
        float c2 = 2.0f * xy.y;
        float tpp = 1.0f, tp = xy.y;
        ty[0] = tp;
#pragma unroll
        for (int m = 1; m < 31; ++m) {
            float tc = c2 * tp - tpp;
            ty[m] = tc;
            tpp = tp; tp = tc;
        }
        ty[31] = 0.0f;                      // pad slot (A k=31 col is zero anyway)
    }

    // Write Tx row (f32, 8x b128; row byte offset l*160, 16B-aligned)
    {
        float* row = &TxL[l * TX_STRIDE];
#pragma unroll
        for (int c = 0; c < 8; ++c) {
            f32x4 v = { tx[4 * c], tx[4 * c + 1], tx[4 * c + 2], tx[4 * c + 3] };
            *reinterpret_cast<f32x4*>(row + 4 * c) = v;
        }
    }
    // Write Ty row (f16, 4x b128; row byte offset l*80, 16B-aligned)
    {
        __fp16* row = &TyL[l * TY_STRIDE];
#pragma unroll
        for (int c = 0; c < 4; ++c) {
            half8_t h;
#pragma unroll
            for (int e = 0; e < 8; ++e) h[e] = (__fp16)ty[8 * c + e];
            *reinterpret_cast<half8_t*>(row + 8 * c) = h;
        }
    }
    __syncthreads();

    // ---- A-fragment preload (wave-invariant, 6 tiles x 16B per lane) ----
    half8_t afrag[6];
#pragma unroll
    for (int t = 0; t < 6; ++t)
        afrag[t] = *reinterpret_cast<const half8_t*>(Wpk + (t * 64 + l) * 8);

    // constant terms
    float c0 = b[0] + W[0 * FEAT];
    float c1 = b[1] + W[1 * FEAT];
    float c2 = b[2] + W[2 * FEAT];

    // ---- 4 groups of 16 points ----
#pragma unroll
    for (int g = 0; g < 4; ++g) {
        int pt = g * 16 + p16;   // this lane's column/point within batch

        // B-fragment: Ty[pt][k = 8q + e]
        half8_t bfrag = *reinterpret_cast<const half8_t*>(&TyL[pt * TY_STRIDE + 8 * q]);
        // Stage-2 Tx values for this lane's D rows: i' = 4q+r and 16+4q+r
        f32x4 txA = *reinterpret_cast<const f32x4*>(&TxL[pt * TX_STRIDE + 4 * q]);
        f32x4 txB = *reinterpret_cast<const f32x4*>(&TxL[pt * TX_STRIDE + 16 + 4 * q]);

        float s0 = 0.f, s1 = 0.f, s2 = 0.f;
#pragma unroll
        for (int t = 0; t < 6; ++t) {
            f32x4 c = { 0.f, 0.f, 0.f, 0.f };
            c = __builtin_amdgcn_mfma_f32_16x16x32_f16(afrag[t], bfrag, c, 0, 0, 0);
            f32x4 ts = (t & 1) ? txB : txA;
            float s = c[0] * ts[0] + c[1] * ts[1] + c[2] * ts[2] + c[3] * ts[3];
            if ((t >> 1) == 0) s0 += s;
            else if ((t >> 1) == 1) s1 += s;
            else s2 += s;
        }
        // reduce over q (lanes differing in bits 4,5)
        s0 += __shfl_xor(s0, 16); s0 += __shfl_xor(s0, 32);
        s1 += __shfl_xor(s1, 16); s1 += __shfl_xor(s1, 32);
        s2 += __shfl_xor(s2, 16); s2 += __shfl_xor(s2, 32);

        // lanes q=0,1,2 store component o=q for point nb+pt
        if (q < 3) {
            float v = (q == 0) ? (s0 + c0) : ((q == 1) ? (s1 + c1) : (s2 + c2));
            out[3 * (nb + pt) + q] = v;
        }
    }
}

extern "C" void kernel_launch(void* const* d_in, const int* in_sizes, int n_in,
                              void* d_out, int out_size, void* d_ws, size_t ws_size,
                              hipStream_t stream) {
    const float* x = (const float*)d_in[0];   // [N,2]
    const float* W = (const float*)d_in[1];   // [3,962]
    const float* b = (const float*)d_in[2];   // [3]
    float* out = (float*)d_out;               // [N,3]
    __fp16* Wpk = (__fp16*)d_ws;              // 6 KB

    int N = in_sizes[0] / 2;                  // 262144 = 64 * 4096, no tail

    pack_w_kernel<<<(6 * 64 * 8 + 255) / 256, 256, 0, stream>>>(W, Wpk);

    int grid = N / 64;
    cheb_mfma_kernel<<<grid, 64, 0, stream>>>(x, W, Wpk, b, out);
}